// Round 11
// baseline (275.726 us; speedup 1.0000x reference)
//
#include <hip/hip_runtime.h>

#define IMG_H 512
#define IMG_W 512
#define BATCH 32
#define TW 256              // block column span (1 col/thread)
#define TH 16               // output rows per block
#define NBLK (2 * 32 * 32)  // 2048 blocks

// ---- 4-row chunk staging: 16 loads -> 16 regs (pf), later 8 ds_write ----
// Depth-1: only ONE chunk in flight (16 floats) => no spill (R6-class
// pressure). The ds_write in STORE data-depends on the loads, so the
// compiler emits a fine-grained vmcnt wait there (not a barrier drain).
#define STAGE(C0, N)                                                          \
  _Pragma("unroll") for (int i = 0; i < 4; ++i) {                             \
    if (i < (N)) {                                                            \
      const int gy = y0 - 3 + (C0) + i;                                       \
      pf[i][0] = pf[i][1] = pf[i][2] = pf[i][3] = 0.f;                        \
      if ((unsigned)gy < (unsigned)IMG_H) { /* wave-uniform */                \
        const float* xrow = Xb + (size_t)gy * IMG_W;                          \
        const float* yrow = Yb + (size_t)gy * IMG_W;                          \
        if (ok1) { pf[i][0] = xrow[g1]; pf[i][1] = yrow[g1]; }                \
        if (ok2) { pf[i][2] = xrow[g2]; pf[i][3] = yrow[g2]; }                \
      }                                                                       \
    }                                                                         \
  }

#define STORE(BUF, N)                                                         \
  _Pragma("unroll") for (int i = 0; i < 4; ++i) {                             \
    if (i < (N)) {                                                            \
      sbuf[BUF][i * 264 + t] = make_float2(pf[i][0], pf[i][1]);               \
      if (t < 6) sbuf[BUF][i * 264 + 256 + t] = make_float2(pf[i][2], pf[i][3]); \
    }                                                                         \
  }

// ---- one input row: h-pass from LDS, vertical ring scatter, emit ---------
// R = absolute tile row (literal), RR = row within chunk, BUF = LDS buffer.
#define ROW_BODY(R, RR, BUF)                                                  \
  {                                                                           \
    float hx = 0.f, hy = 0.f, hxx = 0.f, hyy = 0.f, hxy = 0.f;                \
    _Pragma("unroll") for (int k = 0; k < 7; ++k) {                           \
      const float2 p = sbuf[BUF][(RR)*264 + t + k];                           \
      const float wx = w[k] * p.x;                                            \
      const float wy = w[k] * p.y;                                            \
      hx = fmaf(w[k], p.x, hx);                                               \
      hy = fmaf(w[k], p.y, hy);                                               \
      hxx = fmaf(wx, p.x, hxx);                                               \
      hyy = fmaf(wy, p.y, hyy);                                               \
      hxy = fmaf(wx, p.y, hxy);                                               \
    }                                                                         \
    _Pragma("unroll") for (int tt = 0; tt < 7; ++tt) {                        \
      const int o = (R)-tt;                                                   \
      if (o >= 0 && o < TH) {                                                 \
        const int slot = o % 7;                                               \
        const float wt = w[tt];                                               \
        acc[slot][0] = fmaf(wt, hx, acc[slot][0]);                            \
        acc[slot][1] = fmaf(wt, hy, acc[slot][1]);                            \
        acc[slot][2] = fmaf(wt, hxx, acc[slot][2]);                           \
        acc[slot][3] = fmaf(wt, hyy, acc[slot][3]);                           \
        acc[slot][4] = fmaf(wt, hxy, acc[slot][4]);                           \
      }                                                                       \
    }                                                                         \
    if ((R) >= 6 && (R)-6 < TH) {                                             \
      const int slot = ((R)-6) % 7;                                           \
      const float mu_x = acc[slot][0];                                        \
      const float mu_y = acc[slot][1];                                        \
      const float mx2 = mu_x * mu_x;                                          \
      const float my2 = mu_y * mu_y;                                          \
      const float mxy = mu_x * mu_y;                                          \
      const float sxx = acc[slot][2] - mx2;                                   \
      const float syy = acc[slot][3] - my2;                                   \
      const float sxy = acc[slot][4] - mxy;                                   \
      const float num = (2.f * mxy + 1e-4f) * (2.f * sxy + 9e-4f);            \
      const float den = (mx2 + my2 + 1e-4f) * (sxx + syy + 9e-4f);            \
      tsum += num * __builtin_amdgcn_rcpf(den);                               \
      acc[slot][0] = acc[slot][1] = acc[slot][2] = acc[slot][3] =             \
          acc[slot][4] = 0.f;                                                 \
    }                                                                         \
  }

#define CHUNK(C, BUF, N)                                                      \
  _Pragma("unroll") for (int rr = 0; rr < 4; ++rr) {                          \
    if (rr < (N)) ROW_BODY(4 * (C) + rr, rr, BUF)                             \
  }

__global__ __launch_bounds__(256) void ssim_main(
    const float* __restrict__ X, const float* __restrict__ Y,
    const float* __restrict__ K, float* __restrict__ partials) {
  __shared__ float2 sbuf[2][4 * 264];   // 16896 B, double-buffered chunks
  __shared__ float wsum[4];

  const int t = threadIdx.x;
  const int x0 = blockIdx.x * TW;
  const int y0 = blockIdx.y * TH;
  const size_t img = (size_t)IMG_H * IMG_W;
  const float* Xb = X + blockIdx.z * img;
  const float* Yb = Y + blockIdx.z * img;

  // Exact separable 1D weights from center row of the provided 7x7 kernel:
  // k[3][j] = w3*w_j, sum_j w_j = 1  =>  w_j = k[3][j] / sum_j k[3][j].
  float w[7];
  {
    float rs = 0.f;
#pragma unroll
    for (int j = 0; j < 7; ++j) { w[j] = K[3 * 7 + j]; rs += w[j]; }
    const float inv = 1.f / rs;
#pragma unroll
    for (int j = 0; j < 7; ++j) w[j] *= inv;
  }

  // Loop-invariant horizontal addressing (LDS slot s = image col x0-3+s).
  const int g1 = x0 - 3 + t;
  const bool ok1 = (unsigned)g1 < (unsigned)IMG_W;
  const int g2 = g1 + TW;
  const bool ok2 = (t < 6) && ((unsigned)g2 < (unsigned)IMG_W);

  float acc[7][5];
#pragma unroll
  for (int s = 0; s < 7; ++s)
#pragma unroll
    for (int c = 0; c < 5; ++c) acc[s][c] = 0.f;
  float tsum = 0.f;

  float pf[4][4];   // one 4-row chunk in flight (16 VGPRs, static indices)

  // Pipeline: barrier -> STAGE(next) -> COMPUTE(cur) -> STORE(next) -> ...
  // 6 barriers total; every chunk's loads get ~a full compute phase of cover.
  STAGE(0, 4);
  STORE(0, 4);                           // cold start: fine-grained wait
  __syncthreads();
  STAGE(4, 4);
  CHUNK(0, 0, 4);                        // rows 0-3
  STORE(1, 4);
  __syncthreads();
  STAGE(8, 4);
  CHUNK(1, 1, 4);                        // rows 4-7
  STORE(0, 4);
  __syncthreads();
  STAGE(12, 4);
  CHUNK(2, 0, 4);                        // rows 8-11
  STORE(1, 4);
  __syncthreads();
  STAGE(16, 4);
  CHUNK(3, 1, 4);                        // rows 12-15
  STORE(0, 4);
  __syncthreads();
  STAGE(20, 2);
  CHUNK(4, 0, 4);                        // rows 16-19
  STORE(1, 2);
  __syncthreads();
  CHUNK(5, 1, 2);                        // rows 20-21

  // Block reduction -> one plain store per block.
#pragma unroll
  for (int off = 32; off > 0; off >>= 1) tsum += __shfl_down(tsum, off);
  if ((t & 63) == 0) wsum[t >> 6] = tsum;
  __syncthreads();
  if (t == 0) {
    const int bid = blockIdx.x + 2 * (blockIdx.y + 32 * blockIdx.z);
    partials[bid] = wsum[0] + wsum[1] + wsum[2] + wsum[3];
  }
}

__global__ __launch_bounds__(256) void ssim_reduce(
    const float* __restrict__ partials, float* __restrict__ out) {
  __shared__ double wsum[4];
  const int t = threadIdx.x;
  double s = 0.0;
#pragma unroll
  for (int i = 0; i < NBLK / 256; ++i) s += (double)partials[t + 256 * i];
#pragma unroll
  for (int off = 32; off > 0; off >>= 1) s += __shfl_down(s, off);
  if ((t & 63) == 0) wsum[t >> 6] = s;
  __syncthreads();
  if (t == 0)
    out[0] = (float)((wsum[0] + wsum[1] + wsum[2] + wsum[3]) *
                     (1.0 / (double)((size_t)BATCH * IMG_H * IMG_W)));
}

extern "C" void kernel_launch(void* const* d_in, const int* in_sizes, int n_in,
                              void* d_out, int out_size, void* d_ws, size_t ws_size,
                              hipStream_t stream) {
  const float* X = (const float*)d_in[0];
  const float* Y = (const float*)d_in[1];
  const float* K = (const float*)d_in[2];
  float* out = (float*)d_out;
  float* partials = (float*)d_ws;   // NBLK floats, all rewritten every launch

  dim3 grid(IMG_W / TW, IMG_H / TH, BATCH);  // (2, 32, 32) = 2048 blocks
  hipLaunchKernelGGL(ssim_main, grid, dim3(256), 0, stream, X, Y, K, partials);
  hipLaunchKernelGGL(ssim_reduce, dim3(1), dim3(256), 0, stream, partials, out);
}